// Round 12
// baseline (953.663 us; speedup 1.0000x reference)
//
#include <hip/hip_runtime.h>
#include <math.h>

#define NORB 13
#define NORB2 (NORB * NORB)
#define CAP 128                 // max cached entries per atom (mean 32, sigma ~5.7)
#define KPER 8                  // k-values per WG (K=16 -> KC=2)

typedef float fx4 __attribute__((ext_vector_type(4)));

// block id per orbital index for L_LIST=[0,0,1,1,2] -> sizes 1,1,3,3,5
__device__ __forceinline__ int blk_of(int p) {
    return p < 1 ? 0 : (p < 2 ? 1 : (p < 5 ? 2 : (p < 8 ? 3 : 4)));
}
__device__ __forceinline__ float ffac(int p, int q) {
    int bp = blk_of(p), bq = blk_of(q);
    return bp < bq ? 1.0f : (bp == bq ? 0.5f : 0.0f);
}

// ---- single-WG CSR build, binned by atom a ---------------------------------
// entry = (e<<9) | (rev<<8) | col_atom
__global__ void __launch_bounds__(256)
k_build(const int* __restrict__ edge_index, int* __restrict__ rowptr,
        int* __restrict__ entries, int E, int N) {
    __shared__ int cnt[257], cur[257];
    int tid = threadIdx.x;
    for (int i = tid; i <= N; i += 256) cnt[i] = 0;
    __syncthreads();
    for (int e = tid; e < E; e += 256) {
        int ie = edge_index[e], je = edge_index[E + e];
        atomicAdd(&cnt[ie], 1);
        atomicAdd(&cnt[je], 1);
    }
    __syncthreads();
    if (tid == 0) {
        int run = 0;
        for (int i = 0; i < N; ++i) { rowptr[i] = run; cur[i] = run; run += cnt[i]; }
        rowptr[N] = run;
    }
    __syncthreads();
    for (int e = tid; e < E; e += 256) {
        int ie = edge_index[e], je = edge_index[E + e];
        int pos = atomicAdd(&cur[ie], 1);
        entries[pos] = (e << 9) | je;            // forward: phase * hopF
        pos = atomicAdd(&cur[je], 1);
        entries[pos] = (e << 9) | 256 | ie;      // reverse: conj(phase) * hopF^T
    }
}

// ---- assemble: one WAVE per output row (k-chunk, a, p) ---------------------
// 13 float4 accumulators in registers cover the whole 1664-complex row;
// phase table computed once per WG; r-buckets make all loop bounds uniform.
__global__ void __launch_bounds__(64)
k_assemble(const float* __restrict__ hopping,
           const float* __restrict__ onsite,
           const float* __restrict__ kpoints,
           const float* __restrict__ cell_shift,
           const int* __restrict__ rowptr,
           const int* __restrict__ entries,
           float* __restrict__ out,
           int N, int K, int ld, int es, int KC) {
    int bid = blockIdx.x;
    int kc = bid % KC;
    int p  = (bid / KC) % NORB;
    int a  = bid / (KC * NORB);
    int kper = (K + KC - 1) / KC;
    int k0 = kc * kper, k1 = min(K, k0 + kper);
    int nk = k1 - k0;                            // <= KPER
    int lane = threadIdx.x;

    __shared__ int   s_ent[CAP + 1];
    __shared__ float s_ph[KPER][CAP + 1][2];
    __shared__ int   bcnt[NORB], bptr[NORB + 1], bcur[NORB];
    __shared__ int   blist[2 * (CAP + 1)];

    int beg = rowptr[a], end = rowptr[a + 1];
    int cnt = min(end - beg, CAP);

    for (int n = lane; n < cnt; n += 64) s_ent[n] = entries[beg + n];
    if (lane == 0) s_ent[cnt] = (1 << 30) | a;   // pseudo-entry: onsite diag block
    if (lane < NORB) bcnt[lane] = 0;
    __syncthreads();
    int tot = cnt + 1;

    // phase table: lane n computes its entry's nk phases
    for (int n = lane; n < tot; n += 64) {
        int ent = s_ent[n];
        if (ent & (1 << 30)) {
            for (int kk = 0; kk < nk; ++kk) { s_ph[kk][n][0] = 1.f; s_ph[kk][n][1] = 0.f; }
        } else {
            int e = ent >> 9;
            float Rx = cell_shift[3*e], Ry = cell_shift[3*e+1], Rz = cell_shift[3*e+2];
            for (int kk = 0; kk < nk; ++kk) {
                int k = k0 + kk;
                float d = kpoints[3*k]*Rx + kpoints[3*k+1]*Ry + kpoints[3*k+2]*Rz;
                float s_, c_;
                __sincosf(-6.2831853071795864f * d, &s_, &c_);  // e^{-i2pi d}=c+is
                s_ph[kk][n][0] = c_; s_ph[kk][n][1] = s_;
            }
        }
        // bucket counting (each entry touches r_lo and maybe r_lo+1)
        int b = ent & 255;
        int c_lo = NORB * b;
        int r_lo = (c_lo >> 1) >> 6;
        int r_hi = ((c_lo + NORB - 1) >> 1) >> 6;
        atomicAdd(&bcnt[r_lo], 1);
        if (r_hi != r_lo) atomicAdd(&bcnt[r_hi], 1);
    }
    __syncthreads();
    if (lane == 0) {
        int run = 0;
        for (int r = 0; r < NORB; ++r) { bptr[r] = run; bcur[r] = run; run += bcnt[r]; }
        bptr[NORB] = run;
    }
    __syncthreads();
    for (int n = lane; n < tot; n += 64) {
        int b = s_ent[n] & 255;
        int c_lo = NORB * b;
        int r_lo = (c_lo >> 1) >> 6;
        int r_hi = ((c_lo + NORB - 1) >> 1) >> 6;
        int pos = atomicAdd(&bcur[r_lo], 1); blist[pos] = n;
        if (r_hi != r_lo) { pos = atomicAdd(&bcur[r_hi], 1); blist[pos] = n; }
    }
    __syncthreads();                             // last barrier

    const float* on = onsite + (size_t)a * NORB2;

    if (es == 2 && N == 128) {
        // ---- fast path: ld = 1664, row = 832 float4 = exactly 13 x 64 ----
        fx4* o4 = (fx4*)out;
        for (int kk = 0; kk < nk; ++kk) {
            int k = k0 + kk;
            fx4 acc[13];
#pragma unroll
            for (int r = 0; r < 13; ++r) acc[r] = (fx4){0.f, 0.f, 0.f, 0.f};
#pragma unroll
            for (int r = 0; r < 13; ++r) {
                int ib = bptr[r], ie2 = bptr[r + 1];     // uniform bounds
                for (int ii = ib; ii < ie2; ++ii) {
                    int n = blist[ii];
                    int ent = s_ent[n];
                    int b = ent & 255;
                    int c_lo = NORB * b;
                    int s = lane + (r << 6);
                    int q0 = 2 * s - c_lo, q1 = q0 + 1;
                    float pc = s_ph[kk][n][0], ps = s_ph[kk][n][1];
                    float hv0 = 0.f, hv1 = 0.f;
                    if (ent & (1 << 30)) {
                        if (q0 >= 0 && q0 < NORB)
                            hv0 = on[p*NORB+q0]*ffac(p,q0) + on[q0*NORB+p]*ffac(q0,p);
                        if (q1 >= 0 && q1 < NORB)
                            hv1 = on[p*NORB+q1]*ffac(p,q1) + on[q1*NORB+p]*ffac(q1,p);
                    } else {
                        int e = ent >> 9;
                        int rev = ent & 256;
                        if (rev) ps = -ps;               // conj for reverse
                        const float* h = hopping + (size_t)e * NORB2;
                        if (q0 >= 0 && q0 < NORB)
                            hv0 = rev ? h[q0*NORB+p]*ffac(q0,p) : h[p*NORB+q0]*ffac(p,q0);
                        if (q1 >= 0 && q1 < NORB)
                            hv1 = rev ? h[q1*NORB+p]*ffac(q1,p) : h[p*NORB+q1]*ffac(p,q1);
                    }
                    acc[r].x += pc * hv0; acc[r].y += ps * hv0;
                    acc[r].z += pc * hv1; acc[r].w += ps * hv1;
                }
            }
            // overflow entries beyond CAP (rare): inline, uniform r-skip
            for (int it = beg + CAP; it < end; ++it) {
                int ent = entries[it];
                int b = ent & 255, rev = ent & 256, e = ent >> 9;
                float Rx = cell_shift[3*e], Ry = cell_shift[3*e+1], Rz = cell_shift[3*e+2];
                float d = kpoints[3*k]*Rx + kpoints[3*k+1]*Ry + kpoints[3*k+2]*Rz;
                float s_, c_;
                __sincosf(-6.2831853071795864f * d, &s_, &c_);
                float pc = c_, ps = rev ? -s_ : s_;
                int c_lo = NORB * b;
                int r_lo = (c_lo >> 1) >> 6;
                int r_hi = ((c_lo + NORB - 1) >> 1) >> 6;
                const float* h = hopping + (size_t)e * NORB2;
#pragma unroll
                for (int r = 0; r < 13; ++r) {
                    if (r < r_lo || r > r_hi) continue;  // uniform skip
                    int s = lane + (r << 6);
                    int q0 = 2 * s - c_lo, q1 = q0 + 1;
                    float hv0 = 0.f, hv1 = 0.f;
                    if (q0 >= 0 && q0 < NORB)
                        hv0 = rev ? h[q0*NORB+p]*ffac(q0,p) : h[p*NORB+q0]*ffac(p,q0);
                    if (q1 >= 0 && q1 < NORB)
                        hv1 = rev ? h[q1*NORB+p]*ffac(q1,p) : h[p*NORB+q1]*ffac(p,q1);
                    acc[r].x += pc * hv0; acc[r].y += ps * hv0;
                    acc[r].z += pc * hv1; acc[r].w += ps * hv1;
                }
            }
            size_t base = ((size_t)k * ld + a * NORB + p) * (size_t)(ld / 2);
#pragma unroll
            for (int r = 0; r < 13; ++r)
                o4[base + (r << 6) + lane] = acc[r];     // 1KB/instr, line-aligned
        }
    } else {
        // ---- generic fallback: per complex element, column chunks ----
        int ncol = N * NORB;
        for (int kk = 0; kk < nk; ++kk) {
            int k = k0 + kk;
            for (int c0 = 0; c0 < ncol; c0 += 64) {
                int col = c0 + lane;
                float vre = 0.f, vim = 0.f;
                if (col < ncol) {
                    int b = col / NORB, q = col - b * NORB;
                    if (b == a)
                        vre = on[p*NORB+q]*ffac(p,q) + on[q*NORB+p]*ffac(q,p);
                    for (int n = 0; n < cnt; ++n) {
                        int ent = s_ent[n];
                        if ((ent & 255) != b) continue;
                        int e = ent >> 9, rev = ent & 256;
                        float pc = s_ph[kk][n][0], ps = s_ph[kk][n][1];
                        if (rev) ps = -ps;
                        float hv = rev ? hopping[(size_t)e*NORB2 + q*NORB+p]*ffac(q,p)
                                       : hopping[(size_t)e*NORB2 + p*NORB+q]*ffac(p,q);
                        vre += pc * hv; vim += ps * hv;
                    }
                    for (int it = beg + CAP; it < end; ++it) {
                        int ent = entries[it];
                        if ((ent & 255) != b) continue;
                        int e = ent >> 9, rev = ent & 256;
                        float Rx = cell_shift[3*e], Ry = cell_shift[3*e+1], Rz = cell_shift[3*e+2];
                        float d = kpoints[3*k]*Rx + kpoints[3*k+1]*Ry + kpoints[3*k+2]*Rz;
                        float s_, c_;
                        __sincosf(-6.2831853071795864f * d, &s_, &c_);
                        float hv = rev ? hopping[(size_t)e*NORB2 + q*NORB+p]*ffac(q,p)
                                       : hopping[(size_t)e*NORB2 + p*NORB+q]*ffac(p,q);
                        vre += c_ * hv; vim += (rev ? -s_ : s_) * hv;
                    }
                }
                if (col < ncol) {
                    size_t gc = ((size_t)k * ld + a * NORB + p) * ld + col;
                    if (es == 2) ((float2*)out)[gc] = make_float2(vre, vim);
                    else         out[gc] = vre;
                }
            }
        }
    }
}

extern "C" void kernel_launch(void* const* d_in, const int* in_sizes, int n_in,
                              void* d_out, int out_size, void* d_ws, size_t ws_size,
                              hipStream_t stream) {
    const float* hopping    = (const float*)d_in[0];
    const float* onsite     = (const float*)d_in[1];
    const float* kpoints    = (const float*)d_in[2];
    const float* cell_shift = (const float*)d_in[3];
    const int*   edge_index = (const int*)d_in[4];
    float* out = (float*)d_out;

    int E = in_sizes[0] / NORB2;   // 2048
    int N = in_sizes[1] / NORB2;   // 128
    int K = in_sizes[2] / 3;       // 16
    int ld = N * NORB;             // 1664

    size_t full = (size_t)K * ld * ld * 2;
    int es = ((size_t)out_size >= full) ? 2 : 1;

    // workspace (ints): rowptr[N+1], entries[2E]
    int* rowptr  = (int*)d_ws;
    int* entries = rowptr + N + 1;

    k_build<<<1, 256, 0, stream>>>(edge_index, rowptr, entries, E, N);

    int KC = (K + KPER - 1) / KPER;             // 2 for K=16
    int nwg = N * NORB * KC;                    // 3328 single-wave WGs
    k_assemble<<<nwg, 64, 0, stream>>>(hopping, onsite, kpoints, cell_shift,
                                       rowptr, entries, out, N, K, ld, es, KC);
}